// Round 14
// baseline (403.990 us; speedup 1.0000x reference)
//
#include <hip/hip_runtime.h>
#include <hip/hip_bf16.h>
#include <stdint.h>

#define T_SEQ 4096

typedef float  f32x4   __attribute__((ext_vector_type(4)));
typedef float  f32x16  __attribute__((ext_vector_type(16)));
typedef short  bf16x8  __attribute__((ext_vector_type(8)));
typedef short  s16x4   __attribute__((ext_vector_type(4)));
typedef unsigned int u32x4 __attribute__((ext_vector_type(4)));

typedef const __attribute__((address_space(1))) uint32_t* gptr_t;
typedef __attribute__((address_space(3))) uint32_t* lptr_t;

__device__ __forceinline__ uint32_t f2bf1(float f) {
    uint32_t u = __float_as_uint(f);
    return (u + 0x7fffu + ((u >> 16) & 1u)) >> 16;   // RNE f32->bf16
}
__device__ __forceinline__ short f2bfs(float f) { return (short)f2bf1(f); }
__device__ __forceinline__ uint32_t cvtpk(float lo, float hi) {
    uint32_t r;
    asm("v_cvt_pk_bf16_f32 %0, %1, %2" : "=v"(r) : "v"(lo), "v"(hi));
    return r;
}

// ---------------------------------------------------------------------------
// Kernel 1 (MERGED): all pre-attn prep in ONE launch.
//   blocks [0, 2048):    Q,K projections (4 d/thread, short4 stores)
//   blocks [2048, 2560): V projection transposed (2 t/thread, u32 stores)
//   blocks [2560, 2624): Wout -> Wt bf16 transpose+swizzle; blocks 2560/2561
//                        also zero cnt[512] (finisher counters, per launch).
// ---------------------------------------------------------------------------
__global__ __launch_bounds__(256) void proj_all(
    const float* __restrict__ x,
    const float* __restrict__ Wq1, const float* __restrict__ Wk1,
    const float* __restrict__ Wq2, const float* __restrict__ Wk2,
    const float* __restrict__ Wv1, const float* __restrict__ Wv2,
    const float* __restrict__ Wout,
    short* __restrict__ Q, short* __restrict__ K,
    short* __restrict__ Vt, short* __restrict__ Wt, int* __restrict__ cnt)
{
    int bid = blockIdx.x;
    if (bid < 2048) {
        // ---- Q,K projection: thread owns (b, t, d-quad) ----
        int idx = bid * 256 + threadIdx.x;      // 524288 = 16 dq x 4096 t x 8 b
        int d0 = (idx & 15) * 4;
        int t = (idx >> 4) & (T_SEQ - 1);
        int b = idx >> 16;
        const float* xp = x + (size_t)(b * T_SEQ + t) * 6;
        float x0 = xp[0], x1 = xp[1], x2 = xp[2];
        float x3 = xp[3], x4 = xp[4], x5 = xp[5];
        const float QS = 0.125f * 1.44269504088896340736f;
        s16x4 vq1, vk1, vq2, vk2;
        #pragma unroll
        for (int j = 0; j < 4; ++j) {
            int d = d0 + j;
            float q1 = (x0 * Wq1[d] + x1 * Wq1[64 + d] + x2 * Wq1[128 + d]) * QS;
            float k1 =  x0 * Wk1[d] + x1 * Wk1[64 + d] + x2 * Wk1[128 + d];
            float q2 = (x3 * Wq2[d] + x4 * Wq2[64 + d] + x5 * Wq2[128 + d]) * QS;
            float k2 =  x3 * Wk2[d] + x4 * Wk2[64 + d] + x5 * Wk2[128 + d];
            vq1[j] = f2bfs(q1);  vk1[j] = f2bfs(k1);
            vq2[j] = f2bfs(q2);  vk2[j] = f2bfs(k2);
        }
        size_t base1 = ((size_t)(b * 2 + 0) * T_SEQ + t) * 64 + d0;
        size_t base2 = ((size_t)(b * 2 + 1) * T_SEQ + t) * 64 + d0;
        *(s16x4*)(Q + base1) = vq1;  *(s16x4*)(Q + base2) = vq2;
        *(s16x4*)(K + base1) = vk1;  *(s16x4*)(K + base2) = vk2;
    } else if (bid < 2560) {
        // ---- V projection transposed: Vt[bh][d][t], 2 t per thread ----
        int vb = bid - 2048;
        int bh = vb >> 5;                // 0..15
        int tt = vb & 31;                // 128 t per block
        int head = bh & 1, b = bh >> 1;
        int t  = tt * 128 + 2 * (threadIdx.x & 63);
        int dg = threadIdx.x >> 6;
        const float* Wv = head ? Wv2 : Wv1;
        const float* xp = x + (size_t)(b * T_SEQ + t) * 6 + head * 3;
        float xa0 = xp[0], xa1 = xp[1], xa2 = xp[2];
        float xb0 = xp[6], xb1 = xp[7], xb2 = xp[8];
        size_t base = (size_t)bh * 64 * T_SEQ + t;
        #pragma unroll
        for (int k = 0; k < 16; ++k) {
            int d = dg * 16 + k;
            float va = xa0 * Wv[d] + xa1 * Wv[64 + d] + xa2 * Wv[128 + d];
            float vb2 = xb0 * Wv[d] + xb1 * Wv[64 + d] + xb2 * Wv[128 + d];
            uint32_t pk = f2bf1(va) | (f2bf1(vb2) << 16);
            *(uint32_t*)(Vt + base + (size_t)d * T_SEQ) = pk;
        }
    } else {
        // ---- Wout -> Wt bf16, transposed + xor-swizzled ----
        int tid = (bid - 2560) * 256 + threadIdx.x;   // 16384
        int j = tid >> 7, k = tid & 127;
        float v = Wout[k * 128 + j];
        int slot = k >> 3;
        Wt[j * 128 + (((slot ^ (j & 7)) << 3) | (k & 7))] = f2bfs(v);
        if (bid < 2562) cnt[(bid - 2560) * 256 + threadIdx.x] = 0;  // 512 ints
    }
}

// ---------------------------------------------------------------------------
// Kernel 2: causal flash attention + FUSED out_proj finisher (R14).
//   Main loop + combine VERBATIM R8/R12 (session-best attn structure).
//   Block (s, p): pair s (tiles 64s, 64s+32), chunks c = p, p+2, ... < s+1;
//   emits UNNORMALIZED (acc, l): p=0 -> Hf+L0, p=1 -> P1+L1.
//   R14 finisher: row-group (b, s) = 64 out rows needs 4 blocks' partials
//   (bh=2b/2b+1 x p=0/1 -- all share xcd=b, same-L2 handoff). After combine:
//   release fence + atomicAdd(cnt[b*64+s]); the 4th arriver acquires, stages
//   Wt into its (now free) 32KB LDS, and runs the 64-row out_proj slice
//   (row0 = b*4096 + 64s) -- verbatim R13 out_proj body. Long-first dispatch
//   => most finishers overlap remaining attn compute; out_proj launch + gap
//   vanish. cnt zeroed per launch by proj_all (stream-ordered).
// ---------------------------------------------------------------------------
__global__ __launch_bounds__(256, 4) void attn(
    const short* __restrict__ Q, const short* __restrict__ K,
    const short* __restrict__ Vt, float* __restrict__ Hf,
    float* __restrict__ P1, float* __restrict__ L0, float* __restrict__ L1,
    const short* __restrict__ Wt, int* __restrict__ cnt, float* __restrict__ out)
{
    __shared__ __align__(16) char smem[32768];  // dbuf 2 x (K 8K + V 8K)
    __shared__ int sflag;

    int id = blockIdx.x;                 // 2048
    int xcd = id & 7, rest = id >> 3;    // rest 0..255
    int bh = xcd * 2 + (rest & 1);       // 2 bh per XCD (L2 locality)
    int rem = rest >> 1;                 // 0..127
    int s  = 63 - (rem >> 1);            // pair index, LONGEST FIRST
    int p  = rem & 1;                    // kv-parity half
    int tid = threadIdx.x;
    int W = tid >> 6;
    int lane = tid & 63;
    int ql = lane & 31, h = lane >> 5;
    int tile = W >> 1, half = W & 1;     // wave's (tile, kv-half)
    int t0 = 64 * s + 32 * tile;
    int q  = t0 + ql;
    int n  = s + 1;                      // total 64-kv chunks for this pair
    int nb = (n - p + 1) >> 1;           // my chunk count: ceil((n-p)/2)

    size_t kvbase = (size_t)bh * (T_SEQ * 64);

    // Q fragment (B-operand): lane holds Q[q][ks*16 + h*8 + j]
    bf16x8 qf[4];
    #pragma unroll
    for (int ks = 0; ks < 4; ++ks)
        qf[ks] = *(const bf16x8*)(Q + kvbase + (size_t)q * 64 + ks * 16 + h * 8);

    // staging maps (256 threads): row = tid>>3 (0..31), slot = tid&7,
    // pre-swizzled source column; LDS dest linear (swizzle applied on read).
    int krl = tid >> 3;
    int kcol = ((tid & 7) ^ (krl & 7)) * 8;
    const short* ksrc0 = K + kvbase + kcol;              // + srow*64
    const short* vsrc0 = Vt + kvbase + kcol;             // + d*T_SEQ + kv

    f32x16 acc0, acc1;
    #pragma unroll
    for (int rr = 0; rr < 16; ++rr) { acc0[rr] = 0.f; acc1[rr] = 0.f; }
    float l = 0.f;
    int swz = (ql & 7) << 4;

#define STAGE(bsel, kvv)                                                        \
    {                                                                           \
        char* kb = smem + (bsel) * 16384;                                       \
        char* vb = kb + 8192;                                                   \
        _Pragma("unroll")                                                       \
        for (int z = 0; z < 2; ++z)                                             \
            __builtin_amdgcn_global_load_lds(                                   \
                (gptr_t)(ksrc0 + (size_t)((kvv) + 32 * z + krl) * 64),          \
                (lptr_t)(kb + z * 4096 + tid * 16), 16, 0, 0);                  \
        _Pragma("unroll")                                                       \
        for (int z = 0; z < 2; ++z)                                             \
            __builtin_amdgcn_global_load_lds(                                   \
                (gptr_t)(vsrc0 + (size_t)(32 * z + krl) * T_SEQ + (kvv)),       \
                (lptr_t)(vb + z * 4096 + tid * 16), 16, 0, 0);                  \
    }

#define QK_SM(pf0, pf1)                                                         \
        {                                                                       \
            f32x16 Sv;                                                          \
            _Pragma("unroll") for (int rr = 0; rr < 16; ++rr) Sv[rr] = 0.f;     \
            Sv = __builtin_amdgcn_mfma_f32_32x32x16_bf16(kf0, qf[0], Sv,0,0,0); \
            Sv = __builtin_amdgcn_mfma_f32_32x32x16_bf16(kf1, qf[1], Sv,0,0,0); \
            Sv = __builtin_amdgcn_mfma_f32_32x32x16_bf16(kf2, qf[2], Sv,0,0,0); \
            Sv = __builtin_amdgcn_mfma_f32_32x32x16_bf16(kf3, qf[3], Sv,0,0,0); \
            bool needmask = (kv0 + 32 * half + 31 > t0);  /* max_kv > t0 */     \
            uint32_t pw[8];                                                     \
            float l0 = 0.f, l1 = 0.f;                                           \
            _Pragma("unroll") for (int e = 0; e < 8; ++e) {                     \
                float p0 = __builtin_amdgcn_exp2f(Sv[2 * e]);                   \
                float p1 = __builtin_amdgcn_exp2f(Sv[2 * e + 1]);               \
                if (needmask) {                                                 \
                    int kv = kv0 + 32 * half + 4 * h + 2 * (e & 1) + 8 * (e >> 1); \
                    p0 = (kv     <= q) ? p0 : 0.f;                              \
                    p1 = (kv + 1 <= q) ? p1 : 0.f;                              \
                }                                                               \
                l0 += p0; l1 += p1;                                             \
                pw[e] = cvtpk(p0, p1);                                          \
            }                                                                   \
            l += l0 + l1;                                                       \
            {                                                                   \
                uint32_t a0 = pw[0], b0 = pw[2], a1 = pw[1], b1 = pw[3];        \
                asm("v_permlane32_swap_b32 %0, %1" : "+v"(a0), "+v"(b0));       \
                asm("v_permlane32_swap_b32 %0, %1" : "+v"(a1), "+v"(b1));       \
                u32x4 fr = {a0, a1, b0, b1};                                    \
                pf0 = __builtin_bit_cast(bf16x8, fr);                           \
                uint32_t c0 = pw[4], d0 = pw[6], c1 = pw[5], d1 = pw[7];        \
                asm("v_permlane32_swap_b32 %0, %1" : "+v"(c0), "+v"(d0));       \
                asm("v_permlane32_swap_b32 %0, %1" : "+v"(c1), "+v"(d1));       \
                u32x4 fr1 = {c0, c1, d0, d1};                                   \
                pf1 = __builtin_bit_cast(bf16x8, fr1);                          \
            }                                                                   \
        }

#define BODY(jj)                                                                \
    {                                                                           \
        const int kv0 = 64 * (p + 2 * (jj));                                    \
        if ((jj) + 1 < nb) STAGE(((jj) + 1) & 1, kv0 + 128);                    \
        const char* kb = smem + ((jj) & 1) * 16384;                             \
        const char* vb = kb + 8192;                                             \
        const char* krw = kb + (32 * half + ql) * 128;                          \
        bf16x8 kf0 = *(const bf16x8*)(krw + ((0 * 32 + h * 16) ^ swz));         \
        bf16x8 kf1 = *(const bf16x8*)(krw + ((1 * 32 + h * 16) ^ swz));         \
        bf16x8 kf2 = *(const bf16x8*)(krw + ((2 * 32 + h * 16) ^ swz));         \
        bf16x8 kf3 = *(const bf16x8*)(krw + ((3 * 32 + h * 16) ^ swz));         \
        bool act = (kv0 + 32 * half <= t0 + 31);                                \
        bf16x8 pf0, pf1;                                                        \
        __builtin_amdgcn_s_setprio(1);                                          \
        if (act) QK_SM(pf0, pf1)                                                \
        const char* vr0 = vb + ql * 128;                                        \
        const char* vr1 = vb + (32 + ql) * 128;                                 \
        int vc0 = (64 * half + 16 * h) ^ swz;                                   \
        int vc1 = (64 * half + 32 + 16 * h) ^ swz;                              \
        bf16x8 vf00 = *(const bf16x8*)(vr0 + vc0);                              \
        bf16x8 vf01 = *(const bf16x8*)(vr0 + vc1);                              \
        bf16x8 vf10 = *(const bf16x8*)(vr1 + vc0);                              \
        bf16x8 vf11 = *(const bf16x8*)(vr1 + vc1);                              \
        if (act) {                                                              \
            acc0 = __builtin_amdgcn_mfma_f32_32x32x16_bf16(vf00, pf0, acc0, 0, 0, 0); \
            acc0 = __builtin_amdgcn_mfma_f32_32x32x16_bf16(vf01, pf1, acc0, 0, 0, 0); \
            acc1 = __builtin_amdgcn_mfma_f32_32x32x16_bf16(vf10, pf0, acc1, 0, 0, 0); \
            acc1 = __builtin_amdgcn_mfma_f32_32x32x16_bf16(vf11, pf1, acc1, 0, 0, 0); \
        }                                                                       \
        __builtin_amdgcn_s_setprio(0);                                          \
        __syncthreads();                                                        \
    }

    if (nb > 0) STAGE(0, 64 * p);        // prologue: first chunk -> buf 0
    __syncthreads();

    for (int j = 0; j < nb; ++j) BODY(j);
#undef BODY
#undef QK_SM
#undef STAGE

    // ---- combine: 2 partials/tile. half1 publishes, half0 absorbs+writes
    //      UNNORMALIZED partial (acc, l) to this parity's buffers.
    l += __shfl_xor(l, 32);
    float* sg = (float*)smem + tile * 2112 + lane * 33;  // 2 x [64][33] f32
    if (half == 1) {
        #pragma unroll
        for (int g = 0; g < 4; ++g) {
            *(f32x4*)(sg + 4 * g)      = f32x4{acc0[4*g+0], acc0[4*g+1], acc0[4*g+2], acc0[4*g+3]};
            *(f32x4*)(sg + 16 + 4 * g) = f32x4{acc1[4*g+0], acc1[4*g+1], acc1[4*g+2], acc1[4*g+3]};
        }
        sg[32] = l;
    }
    __syncthreads();
    if (half == 0) {
        #pragma unroll
        for (int g = 0; g < 4; ++g) {
            f32x4 u0 = *(f32x4*)(sg + 4 * g);
            f32x4 u1 = *(f32x4*)(sg + 16 + 4 * g);
            acc0[4*g+0] += u0[0]; acc0[4*g+1] += u0[1]; acc0[4*g+2] += u0[2]; acc0[4*g+3] += u0[3];
            acc1[4*g+0] += u1[0]; acc1[4*g+1] += u1[1]; acc1[4*g+2] += u1[2]; acc1[4*g+3] += u1[3];
        }
        l += sg[32];
        int head = bh & 1, bb = bh >> 1;
        float* Pdst = p ? P1 : Hf;
        float* Ldst = p ? L1 : L0;
        float* hp = Pdst + ((size_t)(bb * T_SEQ) + t0 + ql) * 128 + head * 64 + 4 * h;
        #pragma unroll
        for (int g2 = 0; g2 < 4; ++g2) {
            f32x4 s0 = { acc0[g2*4+0], acc0[g2*4+1], acc0[g2*4+2], acc0[g2*4+3] };
            *(f32x4*)(hp + 8 * g2) = s0;               // d = 8*g2+4h+0..3
            f32x4 s1 = { acc1[g2*4+0], acc1[g2*4+1], acc1[g2*4+2], acc1[g2*4+3] };
            *(f32x4*)(hp + 32 + 8 * g2) = s1;          // d = 32+8*g2+4h+0..3
        }
        if (h == 0)                       // one lane per q-row
            Ldst[(size_t)bh * T_SEQ + t0 + ql] = l;
    }

    // ---- R14 fused finisher: 4th arriver of group (b, s) does out_proj ----
    __syncthreads();                     // all combine stores issued
    __threadfence();                     // release (device scope)
    __syncthreads();
    if (tid == 0) {
        int old = atomicAdd(cnt + ((bh >> 1) * 64 + s), 1);
        sflag = (old == 3) ? 1 : 0;
    }
    __syncthreads();
    if (!sflag) return;
    __threadfence();                     // acquire before reading partials

    {
        // stage Wt into (now free) 32KB LDS -- same pattern as old out_proj
        char* lws = smem;
        int w = tid >> 6, lane2 = tid & 63, c2 = lane2 & 15, g = lane2 >> 4;
        int cs = c2 & 7;
        #pragma unroll
        for (int z = 0; z < 8; ++z)
            __builtin_amdgcn_global_load_lds((gptr_t)(Wt + z * 2048 + w * 512 + lane2 * 8),
                                             (lptr_t)(lws + z * 4096 + w * 1024), 16, 0, 0);
        __syncthreads();                 // drains vmcnt + lgkm

        int bb = bh >> 1;
        int row0 = bb * T_SEQ + 64 * s + w * 16;     // global row base (16 rows)
        int r = row0 + c2;
        int t2 = r & (T_SEQ - 1);
        float rl0 = 1.0f / (L0[(size_t)(bb * 2 + 0) * T_SEQ + t2] + L1[(size_t)(bb * 2 + 0) * T_SEQ + t2]);
        float rl1 = 1.0f / (L0[(size_t)(bb * 2 + 1) * T_SEQ + t2] + L1[(size_t)(bb * 2 + 1) * T_SEQ + t2]);

        bf16x8 af[4];
        const float* hp0 = Hf + (size_t)r * 128 + g * 8;
        const float* hp1 = P1 + (size_t)r * 128 + g * 8;
        #pragma unroll
        for (int kc = 0; kc < 4; ++kc) {
            float rl = (kc < 2) ? rl0 : rl1;      // d = kc*32+g*8+.. ; head = d>>6
            f32x4 x0 = *(const f32x4*)(hp0 + kc * 32);
            f32x4 x1 = *(const f32x4*)(hp0 + kc * 32 + 4);
            f32x4 y0 = *(const f32x4*)(hp1 + kc * 32);
            f32x4 y1 = *(const f32x4*)(hp1 + kc * 32 + 4);
            u32x4 wv = { cvtpk((x0[0]+y0[0])*rl, (x0[1]+y0[1])*rl),
                         cvtpk((x0[2]+y0[2])*rl, (x0[3]+y0[3])*rl),
                         cvtpk((x1[0]+y1[0])*rl, (x1[1]+y1[1])*rl),
                         cvtpk((x1[2]+y1[2])*rl, (x1[3]+y1[3])*rl) };
            af[kc] = __builtin_bit_cast(bf16x8, wv);
        }
        #pragma unroll
        for (int jt = 0; jt < 8; ++jt) {
            f32x4 accum = {0.f, 0.f, 0.f, 0.f};
            #pragma unroll
            for (int kc = 0; kc < 4; ++kc) {
                int row = jt * 16 + c2;
                bf16x8 bfr = *(const bf16x8*)(lws + row * 256 + (((kc * 4 + g) ^ cs) << 4));
                accum = __builtin_amdgcn_mfma_f32_16x16x32_bf16(af[kc], bfr, accum, 0, 0, 0);
            }
            #pragma unroll
            for (int rr = 0; rr < 4; ++rr)
                out[(size_t)(row0 + g * 4 + rr) * 128 + jt * 16 + c2] = accum[rr];
        }
    }
}

// ---------------------------------------------------------------------------
extern "C" void kernel_launch(void* const* d_in, const int* in_sizes, int n_in,
                              void* d_out, int out_size, void* d_ws, size_t ws_size,
                              hipStream_t stream)
{
    (void)in_sizes; (void)n_in; (void)out_size; (void)ws_size;
    const float* x    = (const float*)d_in[0];
    const float* Wq1  = (const float*)d_in[1];
    const float* Wk1  = (const float*)d_in[2];
    const float* Wv1  = (const float*)d_in[3];
    const float* Wq2  = (const float*)d_in[4];
    const float* Wk2  = (const float*)d_in[5];
    const float* Wv2  = (const float*)d_in[6];
    const float* Wout = (const float*)d_in[7];
    float* out = (float*)d_out;

    char* ws = (char*)d_ws;
    short* Q  = (short*)(ws);                               // 8 MiB
    short* K  = (short*)(ws + (size_t)8  * 1024 * 1024);    // 8 MiB
    short* Vt = (short*)(ws + (size_t)16 * 1024 * 1024);    // 8 MiB
    float* P1 = (float*)(ws + (size_t)24 * 1024 * 1024);    // 16 MiB partial
    float* L0 = (float*)(ws + (size_t)40 * 1024 * 1024);    // 256 KiB
    float* L1 = (float*)(ws + (size_t)40 * 1024 * 1024 + 262144);
    short* Wt = (short*)(ws + (size_t)40 * 1024 * 1024 + 524288);  // 32 KiB
    int*  cnt = (int*)  (ws + (size_t)40 * 1024 * 1024 + 557056);  // 2 KiB
    float* Hf = out;                                        // P0 lives in d_out

    proj_all<<<2624, 256, 0, stream>>>(x, Wq1, Wk1, Wq2, Wk2, Wv1, Wv2, Wout,
                                       Q, K, Vt, Wt, cnt);
    attn    <<<2048, 256, 0, stream>>>(Q, K, Vt, Hf, P1, L0, L1, Wt, cnt, out);
}

// Round 15
// 81.982 us; speedup vs baseline: 4.9278x; 4.9278x over previous
//
#include <hip/hip_runtime.h>
#include <hip/hip_bf16.h>
#include <stdint.h>

#define T_SEQ 4096

typedef float  f32x4   __attribute__((ext_vector_type(4)));
typedef float  f32x16  __attribute__((ext_vector_type(16)));
typedef short  bf16x8  __attribute__((ext_vector_type(8)));
typedef short  s16x4   __attribute__((ext_vector_type(4)));
typedef unsigned int u32x4 __attribute__((ext_vector_type(4)));

typedef const __attribute__((address_space(1))) uint32_t* gptr_t;
typedef __attribute__((address_space(3))) uint32_t* lptr_t;

__device__ __forceinline__ uint32_t f2bf1(float f) {
    uint32_t u = __float_as_uint(f);
    return (u + 0x7fffu + ((u >> 16) & 1u)) >> 16;   // RNE f32->bf16
}
__device__ __forceinline__ short f2bfs(float f) { return (short)f2bf1(f); }
__device__ __forceinline__ uint32_t cvtpk(float lo, float hi) {
    uint32_t r;
    asm("v_cvt_pk_bf16_f32 %0, %1, %2" : "=v"(r) : "v"(lo), "v"(hi));
    return r;
}

// ---------------------------------------------------------------------------
// Kernel 1 (MERGED): all pre-attn prep in ONE launch (removes 2 launch gaps).
//   blocks [0, 2048):    Q,K projections (4 d/thread, short4 stores)
//   blocks [2048, 2560): V projection transposed (2 t/thread, u32 stores)
//   blocks [2560, 2624): Wout -> Wt bf16 transpose+swizzle
// ---------------------------------------------------------------------------
__global__ __launch_bounds__(256) void proj_all(
    const float* __restrict__ x,
    const float* __restrict__ Wq1, const float* __restrict__ Wk1,
    const float* __restrict__ Wq2, const float* __restrict__ Wk2,
    const float* __restrict__ Wv1, const float* __restrict__ Wv2,
    const float* __restrict__ Wout,
    short* __restrict__ Q, short* __restrict__ K,
    short* __restrict__ Vt, short* __restrict__ Wt)
{
    int bid = blockIdx.x;
    if (bid < 2048) {
        // ---- Q,K projection: thread owns (b, t, d-quad) ----
        int idx = bid * 256 + threadIdx.x;      // 524288 = 16 dq x 4096 t x 8 b
        int d0 = (idx & 15) * 4;
        int t = (idx >> 4) & (T_SEQ - 1);
        int b = idx >> 16;
        const float* xp = x + (size_t)(b * T_SEQ + t) * 6;
        float x0 = xp[0], x1 = xp[1], x2 = xp[2];
        float x3 = xp[3], x4 = xp[4], x5 = xp[5];
        const float QS = 0.125f * 1.44269504088896340736f;
        s16x4 vq1, vk1, vq2, vk2;
        #pragma unroll
        for (int j = 0; j < 4; ++j) {
            int d = d0 + j;
            float q1 = (x0 * Wq1[d] + x1 * Wq1[64 + d] + x2 * Wq1[128 + d]) * QS;
            float k1 =  x0 * Wk1[d] + x1 * Wk1[64 + d] + x2 * Wk1[128 + d];
            float q2 = (x3 * Wq2[d] + x4 * Wq2[64 + d] + x5 * Wq2[128 + d]) * QS;
            float k2 =  x3 * Wk2[d] + x4 * Wk2[64 + d] + x5 * Wk2[128 + d];
            vq1[j] = f2bfs(q1);  vk1[j] = f2bfs(k1);
            vq2[j] = f2bfs(q2);  vk2[j] = f2bfs(k2);
        }
        size_t base1 = ((size_t)(b * 2 + 0) * T_SEQ + t) * 64 + d0;
        size_t base2 = ((size_t)(b * 2 + 1) * T_SEQ + t) * 64 + d0;
        *(s16x4*)(Q + base1) = vq1;  *(s16x4*)(Q + base2) = vq2;
        *(s16x4*)(K + base1) = vk1;  *(s16x4*)(K + base2) = vk2;
    } else if (bid < 2560) {
        // ---- V projection transposed: Vt[bh][d][t], 2 t per thread ----
        int vb = bid - 2048;
        int bh = vb >> 5;                // 0..15
        int tt = vb & 31;                // 128 t per block
        int head = bh & 1, b = bh >> 1;
        int t  = tt * 128 + 2 * (threadIdx.x & 63);
        int dg = threadIdx.x >> 6;
        const float* Wv = head ? Wv2 : Wv1;
        const float* xp = x + (size_t)(b * T_SEQ + t) * 6 + head * 3;
        float xa0 = xp[0], xa1 = xp[1], xa2 = xp[2];
        float xb0 = xp[6], xb1 = xp[7], xb2 = xp[8];
        size_t base = (size_t)bh * 64 * T_SEQ + t;
        #pragma unroll
        for (int k = 0; k < 16; ++k) {
            int d = dg * 16 + k;
            float va = xa0 * Wv[d] + xa1 * Wv[64 + d] + xa2 * Wv[128 + d];
            float vb2 = xb0 * Wv[d] + xb1 * Wv[64 + d] + xb2 * Wv[128 + d];
            uint32_t pk = f2bf1(va) | (f2bf1(vb2) << 16);
            *(uint32_t*)(Vt + base + (size_t)d * T_SEQ) = pk;
        }
    } else {
        // ---- Wout -> Wt bf16, transposed + xor-swizzled ----
        int tid = (bid - 2560) * 256 + threadIdx.x;   // 16384
        int j = tid >> 7, k = tid & 127;
        float v = Wout[k * 128 + j];
        int slot = k >> 3;
        Wt[j * 128 + (((slot ^ (j & 7)) << 3) | (k & 7))] = f2bfs(v);
    }
}

// ---------------------------------------------------------------------------
// Kernel 2: causal flash attention, (tile, kv-half) waves + KV-SPLIT blocks.
//   VERBATIM R8/R12/R13 (session-best attn: 65.7us). Structural probes all
//   null/negative (R5 balance, R7 occupancy, R9 fold, R10 V-in-regs, R11
//   counted-vmcnt, R14 fused finisher -6x): this wave-level structure sits
//   at a distributed latency/sync equilibrium (no pipe >50%).
//   Block (s, p): pair s (tiles 64s, 64s+32), chunks c = p, p+2, ... < s+1
//   -> <= 32 bodies; static-max softmax => partials additive: emits
//   UNNORMALIZED acc and l. p=0 -> Hf+L0; p=1 -> P1+L1. out_proj combines.
// ---------------------------------------------------------------------------
__global__ __launch_bounds__(256, 4) void attn(
    const short* __restrict__ Q, const short* __restrict__ K,
    const short* __restrict__ Vt, float* __restrict__ Hf,
    float* __restrict__ P1, float* __restrict__ L0, float* __restrict__ L1)
{
    __shared__ __align__(16) char smem[32768];  // dbuf 2 x (K 8K + V 8K)

    int id = blockIdx.x;                 // 2048
    int xcd = id & 7, rest = id >> 3;    // rest 0..255
    int bh = xcd * 2 + (rest & 1);       // 2 bh per XCD (L2 locality)
    int rem = rest >> 1;                 // 0..127
    int s  = 63 - (rem >> 1);            // pair index, LONGEST FIRST
    int p  = rem & 1;                    // kv-parity half
    int tid = threadIdx.x;
    int W = tid >> 6;
    int lane = tid & 63;
    int ql = lane & 31, h = lane >> 5;
    int tile = W >> 1, half = W & 1;     // wave's (tile, kv-half)
    int t0 = 64 * s + 32 * tile;
    int q  = t0 + ql;
    int n  = s + 1;                      // total 64-kv chunks for this pair
    int nb = (n - p + 1) >> 1;           // my chunk count: ceil((n-p)/2)

    size_t kvbase = (size_t)bh * (T_SEQ * 64);

    // Q fragment (B-operand): lane holds Q[q][ks*16 + h*8 + j]
    bf16x8 qf[4];
    #pragma unroll
    for (int ks = 0; ks < 4; ++ks)
        qf[ks] = *(const bf16x8*)(Q + kvbase + (size_t)q * 64 + ks * 16 + h * 8);

    // staging maps (256 threads): row = tid>>3 (0..31), slot = tid&7,
    // pre-swizzled source column; LDS dest linear (swizzle applied on read).
    int krl = tid >> 3;
    int kcol = ((tid & 7) ^ (krl & 7)) * 8;
    const short* ksrc0 = K + kvbase + kcol;              // + srow*64
    const short* vsrc0 = Vt + kvbase + kcol;             // + d*T_SEQ + kv

    f32x16 acc0, acc1;
    #pragma unroll
    for (int rr = 0; rr < 16; ++rr) { acc0[rr] = 0.f; acc1[rr] = 0.f; }
    float l = 0.f;
    int swz = (ql & 7) << 4;

#define STAGE(bsel, kvv)                                                        \
    {                                                                           \
        char* kb = smem + (bsel) * 16384;                                       \
        char* vb = kb + 8192;                                                   \
        _Pragma("unroll")                                                       \
        for (int z = 0; z < 2; ++z)                                             \
            __builtin_amdgcn_global_load_lds(                                   \
                (gptr_t)(ksrc0 + (size_t)((kvv) + 32 * z + krl) * 64),          \
                (lptr_t)(kb + z * 4096 + tid * 16), 16, 0, 0);                  \
        _Pragma("unroll")                                                       \
        for (int z = 0; z < 2; ++z)                                             \
            __builtin_amdgcn_global_load_lds(                                   \
                (gptr_t)(vsrc0 + (size_t)(32 * z + krl) * T_SEQ + (kvv)),       \
                (lptr_t)(vb + z * 4096 + tid * 16), 16, 0, 0);                  \
    }

#define QK_SM(pf0, pf1)                                                         \
        {                                                                       \
            f32x16 Sv;                                                          \
            _Pragma("unroll") for (int rr = 0; rr < 16; ++rr) Sv[rr] = 0.f;     \
            Sv = __builtin_amdgcn_mfma_f32_32x32x16_bf16(kf0, qf[0], Sv,0,0,0); \
            Sv = __builtin_amdgcn_mfma_f32_32x32x16_bf16(kf1, qf[1], Sv,0,0,0); \
            Sv = __builtin_amdgcn_mfma_f32_32x32x16_bf16(kf2, qf[2], Sv,0,0,0); \
            Sv = __builtin_amdgcn_mfma_f32_32x32x16_bf16(kf3, qf[3], Sv,0,0,0); \
            bool needmask = (kv0 + 32 * half + 31 > t0);  /* max_kv > t0 */     \
            uint32_t pw[8];                                                     \
            float l0 = 0.f, l1 = 0.f;                                           \
            _Pragma("unroll") for (int e = 0; e < 8; ++e) {                     \
                float p0 = __builtin_amdgcn_exp2f(Sv[2 * e]);                   \
                float p1 = __builtin_amdgcn_exp2f(Sv[2 * e + 1]);               \
                if (needmask) {                                                 \
                    int kv = kv0 + 32 * half + 4 * h + 2 * (e & 1) + 8 * (e >> 1); \
                    p0 = (kv     <= q) ? p0 : 0.f;                              \
                    p1 = (kv + 1 <= q) ? p1 : 0.f;                              \
                }                                                               \
                l0 += p0; l1 += p1;                                             \
                pw[e] = cvtpk(p0, p1);                                          \
            }                                                                   \
            l += l0 + l1;                                                       \
            {                                                                   \
                uint32_t a0 = pw[0], b0 = pw[2], a1 = pw[1], b1 = pw[3];        \
                asm("v_permlane32_swap_b32 %0, %1" : "+v"(a0), "+v"(b0));       \
                asm("v_permlane32_swap_b32 %0, %1" : "+v"(a1), "+v"(b1));       \
                u32x4 fr = {a0, a1, b0, b1};                                    \
                pf0 = __builtin_bit_cast(bf16x8, fr);                           \
                uint32_t c0 = pw[4], d0 = pw[6], c1 = pw[5], d1 = pw[7];        \
                asm("v_permlane32_swap_b32 %0, %1" : "+v"(c0), "+v"(d0));       \
                asm("v_permlane32_swap_b32 %0, %1" : "+v"(c1), "+v"(d1));       \
                u32x4 fr1 = {c0, c1, d0, d1};                                   \
                pf1 = __builtin_bit_cast(bf16x8, fr1);                          \
            }                                                                   \
        }

#define BODY(jj)                                                                \
    {                                                                           \
        const int kv0 = 64 * (p + 2 * (jj));                                    \
        if ((jj) + 1 < nb) STAGE(((jj) + 1) & 1, kv0 + 128);                    \
        const char* kb = smem + ((jj) & 1) * 16384;                             \
        const char* vb = kb + 8192;                                             \
        const char* krw = kb + (32 * half + ql) * 128;                          \
        bf16x8 kf0 = *(const bf16x8*)(krw + ((0 * 32 + h * 16) ^ swz));         \
        bf16x8 kf1 = *(const bf16x8*)(krw + ((1 * 32 + h * 16) ^ swz));         \
        bf16x8 kf2 = *(const bf16x8*)(krw + ((2 * 32 + h * 16) ^ swz));         \
        bf16x8 kf3 = *(const bf16x8*)(krw + ((3 * 32 + h * 16) ^ swz));         \
        bool act = (kv0 + 32 * half <= t0 + 31);                                \
        bf16x8 pf0, pf1;                                                        \
        __builtin_amdgcn_s_setprio(1);                                          \
        if (act) QK_SM(pf0, pf1)                                                \
        const char* vr0 = vb + ql * 128;                                        \
        const char* vr1 = vb + (32 + ql) * 128;                                 \
        int vc0 = (64 * half + 16 * h) ^ swz;                                   \
        int vc1 = (64 * half + 32 + 16 * h) ^ swz;                              \
        bf16x8 vf00 = *(const bf16x8*)(vr0 + vc0);                              \
        bf16x8 vf01 = *(const bf16x8*)(vr0 + vc1);                              \
        bf16x8 vf10 = *(const bf16x8*)(vr1 + vc0);                              \
        bf16x8 vf11 = *(const bf16x8*)(vr1 + vc1);                              \
        if (act) {                                                              \
            acc0 = __builtin_amdgcn_mfma_f32_32x32x16_bf16(vf00, pf0, acc0, 0, 0, 0); \
            acc0 = __builtin_amdgcn_mfma_f32_32x32x16_bf16(vf01, pf1, acc0, 0, 0, 0); \
            acc1 = __builtin_amdgcn_mfma_f32_32x32x16_bf16(vf10, pf0, acc1, 0, 0, 0); \
            acc1 = __builtin_amdgcn_mfma_f32_32x32x16_bf16(vf11, pf1, acc1, 0, 0, 0); \
        }                                                                       \
        __builtin_amdgcn_s_setprio(0);                                          \
        __syncthreads();                                                        \
    }

    if (nb > 0) STAGE(0, 64 * p);        // prologue: first chunk -> buf 0
    __syncthreads();

    for (int j = 0; j < nb; ++j) BODY(j);
#undef BODY
#undef QK_SM
#undef STAGE

    // ---- combine: 2 partials/tile. half1 publishes, half0 absorbs+writes
    //      UNNORMALIZED partial (acc, l) to this parity's buffers.
    l += __shfl_xor(l, 32);
    float* sg = (float*)smem + tile * 2112 + lane * 33;  // 2 x [64][33] f32
    if (half == 1) {
        #pragma unroll
        for (int g = 0; g < 4; ++g) {
            *(f32x4*)(sg + 4 * g)      = f32x4{acc0[4*g+0], acc0[4*g+1], acc0[4*g+2], acc0[4*g+3]};
            *(f32x4*)(sg + 16 + 4 * g) = f32x4{acc1[4*g+0], acc1[4*g+1], acc1[4*g+2], acc1[4*g+3]};
        }
        sg[32] = l;
    }
    __syncthreads();
    if (half == 0) {
        #pragma unroll
        for (int g = 0; g < 4; ++g) {
            f32x4 u0 = *(f32x4*)(sg + 4 * g);
            f32x4 u1 = *(f32x4*)(sg + 16 + 4 * g);
            acc0[4*g+0] += u0[0]; acc0[4*g+1] += u0[1]; acc0[4*g+2] += u0[2]; acc0[4*g+3] += u0[3];
            acc1[4*g+0] += u1[0]; acc1[4*g+1] += u1[1]; acc1[4*g+2] += u1[2]; acc1[4*g+3] += u1[3];
        }
        l += sg[32];
        int head = bh & 1, bb = bh >> 1;
        float* Pdst = p ? P1 : Hf;
        float* Ldst = p ? L1 : L0;
        float* hp = Pdst + ((size_t)(bb * T_SEQ) + t0 + ql) * 128 + head * 64 + 4 * h;
        #pragma unroll
        for (int g2 = 0; g2 < 4; ++g2) {
            f32x4 s0 = { acc0[g2*4+0], acc0[g2*4+1], acc0[g2*4+2], acc0[g2*4+3] };
            *(f32x4*)(hp + 8 * g2) = s0;               // d = 8*g2+4h+0..3
            f32x4 s1 = { acc1[g2*4+0], acc1[g2*4+1], acc1[g2*4+2], acc1[g2*4+3] };
            *(f32x4*)(hp + 32 + 8 * g2) = s1;          // d = 32+8*g2+4h+0..3
        }
        if (h == 0)                       // one lane per q-row
            Ldst[(size_t)bh * T_SEQ + t0 + ql] = l;
    }
}

// ---------------------------------------------------------------------------
// Kernel 3: out = ((P0+P1) * 1/(L0+L1)) @ Wout -> f32 (in place over P0).
// Row-block-diagonal: each wave reads only its own 16 rows before writing.
// Normalization folded into the bf16 fragment build (per-head rl).
// ---------------------------------------------------------------------------
__global__ __launch_bounds__(256) void out_proj(
    const float* P0, const float* __restrict__ P1,
    const float* __restrict__ L0, const float* __restrict__ L1,
    const short* __restrict__ Wt, float* out)
{
    __shared__ __align__(16) char lws[32768];
    int tid = threadIdx.x;
    int w = tid >> 6, lane = tid & 63, c = lane & 15, g = lane >> 4;
    int cs = c & 7;
    #pragma unroll
    for (int z = 0; z < 8; ++z)
        __builtin_amdgcn_global_load_lds((gptr_t)(Wt + z * 2048 + w * 512 + lane * 8),
                                         (lptr_t)(lws + z * 4096 + w * 1024), 16, 0, 0);
    __syncthreads();

    int row0 = blockIdx.x * 64 + w * 16;
    int r = row0 + c;
    int b = r >> 12, t = r & (T_SEQ - 1);
    float rl0 = 1.0f / (L0[(size_t)(b * 2 + 0) * T_SEQ + t] + L1[(size_t)(b * 2 + 0) * T_SEQ + t]);
    float rl1 = 1.0f / (L0[(size_t)(b * 2 + 1) * T_SEQ + t] + L1[(size_t)(b * 2 + 1) * T_SEQ + t]);

    bf16x8 af[4];
    const float* hp0 = P0 + (size_t)r * 128 + g * 8;
    const float* hp1 = P1 + (size_t)r * 128 + g * 8;
    #pragma unroll
    for (int kc = 0; kc < 4; ++kc) {
        float rl = (kc < 2) ? rl0 : rl1;          // d = kc*32+g*8+.. ; head = d>>6
        f32x4 x0 = *(const f32x4*)(hp0 + kc * 32);
        f32x4 x1 = *(const f32x4*)(hp0 + kc * 32 + 4);
        f32x4 y0 = *(const f32x4*)(hp1 + kc * 32);
        f32x4 y1 = *(const f32x4*)(hp1 + kc * 32 + 4);
        u32x4 wv = { cvtpk((x0[0]+y0[0])*rl, (x0[1]+y0[1])*rl),
                     cvtpk((x0[2]+y0[2])*rl, (x0[3]+y0[3])*rl),
                     cvtpk((x1[0]+y1[0])*rl, (x1[1]+y1[1])*rl),
                     cvtpk((x1[2]+y1[2])*rl, (x1[3]+y1[3])*rl) };
        af[kc] = __builtin_bit_cast(bf16x8, wv);
    }
    #pragma unroll
    for (int jt = 0; jt < 8; ++jt) {
        f32x4 accum = {0.f, 0.f, 0.f, 0.f};
        #pragma unroll
        for (int kc = 0; kc < 4; ++kc) {
            int row = jt * 16 + c;
            bf16x8 bfr = *(const bf16x8*)(lws + row * 256 + (((kc * 4 + g) ^ cs) << 4));
            accum = __builtin_amdgcn_mfma_f32_16x16x32_bf16(af[kc], bfr, accum, 0, 0, 0);
        }
        #pragma unroll
        for (int rr = 0; rr < 4; ++rr)
            out[(size_t)(row0 + g * 4 + rr) * 128 + jt * 16 + c] = accum[rr];
    }
}

// ---------------------------------------------------------------------------
extern "C" void kernel_launch(void* const* d_in, const int* in_sizes, int n_in,
                              void* d_out, int out_size, void* d_ws, size_t ws_size,
                              hipStream_t stream)
{
    (void)in_sizes; (void)n_in; (void)out_size; (void)ws_size;
    const float* x    = (const float*)d_in[0];
    const float* Wq1  = (const float*)d_in[1];
    const float* Wk1  = (const float*)d_in[2];
    const float* Wv1  = (const float*)d_in[3];
    const float* Wq2  = (const float*)d_in[4];
    const float* Wk2  = (const float*)d_in[5];
    const float* Wv2  = (const float*)d_in[6];
    const float* Wout = (const float*)d_in[7];
    float* out = (float*)d_out;

    char* ws = (char*)d_ws;
    short* Q  = (short*)(ws);                               // 8 MiB
    short* K  = (short*)(ws + (size_t)8  * 1024 * 1024);    // 8 MiB
    short* Vt = (short*)(ws + (size_t)16 * 1024 * 1024);    // 8 MiB
    float* P1 = (float*)(ws + (size_t)24 * 1024 * 1024);    // 16 MiB partial
    float* L0 = (float*)(ws + (size_t)40 * 1024 * 1024);    // 256 KiB
    float* L1 = (float*)(ws + (size_t)40 * 1024 * 1024 + 262144);
    short* Wt = (short*)(ws + (size_t)40 * 1024 * 1024 + 524288);  // 32 KiB (own slot)
    float* Hf = out;                                        // P0 lives in d_out

    proj_all<<<2624, 256, 0, stream>>>(x, Wq1, Wk1, Wq2, Wk2, Wv1, Wv2, Wout,
                                       Q, K, Vt, Wt);
    attn    <<<2048, 256, 0, stream>>>(Q, K, Vt, Hf, P1, L0, L1);
    out_proj<<< 512, 256, 0, stream>>>(Hf, P1, L0, L1, Wt, out);
}